// Round 3
// baseline (450.387 us; speedup 1.0000x reference)
//
#include <hip/hip_runtime.h>
#include <stdint.h>

// Problem constants
#define kB  16384
#define kD  1024
#define kDE 512

typedef __bf16 bf16x8 __attribute__((ext_vector_type(8)));
typedef float  f32x4  __attribute__((ext_vector_type(4)));

__device__ __forceinline__ unsigned short f2bf(float f) {
    union { float f; unsigned u; } v; v.f = f;
    unsigned r = v.u + 0x7FFFu + ((v.u >> 16) & 1u);   // round-to-nearest-even
    return (unsigned short)(r >> 16);
}

__device__ __forceinline__ void async16(unsigned short* lds, const unsigned short* g) {
    __builtin_amdgcn_global_load_lds(
        (const __attribute__((address_space(1))) unsigned int*)g,
        (__attribute__((address_space(3))) unsigned int*)lds, 16, 0, 0);
}

// ---------------- prep: transpose + convert weights to bf16 ----------------
__global__ __launch_bounds__(256) void prep_w(const float* __restrict__ Wsh,
                                              const float* __restrict__ Wsp,
                                              unsigned short* __restrict__ Wt) {
    __shared__ float tile[32][33];
    const int slot = blockIdx.z;
    const int k0 = blockIdx.x * 32;
    const int n0 = blockIdx.y * 32;
    const float* src = (slot < 4) ? (Wsh + (size_t)slot * kD * kDE)
                                  : (Wsp + (size_t)(slot - 4) * kD * kDE);
    const int tx = threadIdx.x, ty = threadIdx.y;
#pragma unroll
    for (int i = 0; i < 4; i++)
        tile[ty + i * 8][tx] = src[(size_t)(k0 + ty + i * 8) * kDE + n0 + tx];
    __syncthreads();
    unsigned short* dst = Wt + (size_t)slot * kDE * kD;
#pragma unroll
    for (int i = 0; i < 4; i++)
        dst[(size_t)(n0 + ty + i * 8) * kD + k0 + tx] = f2bf(tile[tx][ty + i * 8]);
}

// bias concat: bc[t][e][n]  (2*8*512)
__global__ __launch_bounds__(256) void prep_b(const float* __restrict__ bsh,
                                              const float* __restrict__ bsp,
                                              float* __restrict__ bc) {
    int i = blockIdx.x * 256 + threadIdx.x;
    int n = i & 511, e = (i >> 9) & 7, t = i >> 12;
    bc[i] = (e < 4) ? bsh[e * 512 + n] : bsp[(t * 4 + (e - 4)) * 512 + n];
}

// ------------- fused x fp32->bf16 conversion + gate softmax ---------------
__global__ __launch_bounds__(256) void conv_gate(
    const float* __restrict__ x0, const float* __restrict__ x1,
    const float* __restrict__ Wg, const float* __restrict__ bg,
    unsigned short* __restrict__ xb, float* __restrict__ g) {
    const int wid = threadIdx.x >> 6, lane = threadIdx.x & 63;
    const int r = blockIdx.x * 4 + wid;
    const int t = r >> 14, b = r & 16383;
    const float* xrow = (t ? x1 : x0) + (size_t)b * kD;
    unsigned short* xbrow = xb + (size_t)(t * kB + b) * kD;
    const float* Wgt = Wg + t * kD * 8;
    float p[8] = {0.f,0.f,0.f,0.f,0.f,0.f,0.f,0.f};
#pragma unroll
    for (int it = 0; it < 4; it++) {
        const int d0 = it * 256 + lane * 4;
        const float4 v = *(const float4*)(xrow + d0);
        ushort4 h;
        h.x = f2bf(v.x); h.y = f2bf(v.y); h.z = f2bf(v.z); h.w = f2bf(v.w);
        *(ushort4*)(xbrow + d0) = h;
        const float xv[4] = {v.x, v.y, v.z, v.w};
#pragma unroll
        for (int j = 0; j < 4; j++) {
            const float* wrow = Wgt + (size_t)(d0 + j) * 8;
#pragma unroll
            for (int e = 0; e < 8; e++) p[e] += xv[j] * wrow[e];
        }
    }
#pragma unroll
    for (int e = 0; e < 8; e++) {
        float v = p[e];
#pragma unroll
        for (int s = 1; s < 64; s <<= 1) v += __shfl_xor(v, s, 64);
        p[e] = v;
    }
    float lg[8];
#pragma unroll
    for (int e = 0; e < 8; e++) lg[e] = p[e] + bg[t * 8 + e];
    float mx = lg[0];
#pragma unroll
    for (int e = 1; e < 8; e++) mx = fmaxf(mx, lg[e]);
    float s = 0.f;
#pragma unroll
    for (int e = 0; e < 8; e++) { lg[e] = __expf(lg[e] - mx); s += lg[e]; }
    const float inv = 1.f / s;
    if (lane == 0) {
        float* gp = g + (size_t)(t * kB + b) * 8;
        float4 g0 = {lg[0]*inv, lg[1]*inv, lg[2]*inv, lg[3]*inv};
        float4 g1 = {lg[4]*inv, lg[5]*inv, lg[6]*inv, lg[7]*inv};
        *(float4*)gp = g0;
        *(float4*)(gp + 4) = g1;
    }
}

// --------------------------- fused MoE GEMM -------------------------------
// Experts inner; M=128 x (8 experts x 64) per block; 8 waves (2Mx4N).
// 4-phase K-step (m201 template): {reads || stage-part, barrier, lgkmcnt(0),
// setprio, 16 MFMA, setprio}; counted vmcnt(2) once per step; K-loop
// unrolled x2 so LDS buffer indices are compile-time constants.
__global__ __launch_bounds__(512, 2) void moe_gemm(
    const unsigned short* __restrict__ xb, const unsigned short* __restrict__ Wt,
    const float* __restrict__ g, const float* __restrict__ bc,
    float* __restrict__ out) {
    __shared__ __align__(16) unsigned short As[2][128 * 64];      // 32 KB
    __shared__ __align__(16) unsigned short Bs[2][8 * 64 * 64];   // 128 KB

    // XCD-bijective swizzle (nwg=2048, %8==0)
    const int bid = blockIdx.x;
    const int swz = (bid & 7) * 256 + (bid >> 3);
    const int ct = swz & 7;
    const int rt = (swz >> 3) & 127;
    const int t  = swz >> 10;
    const int n0 = ct * 64;

    const int tid = threadIdx.x, wid = tid >> 6, lane = tid & 63;
    const int wr = wid >> 2, wc = wid & 3;

    // staging (pre-swizzled global source, linear LDS dest — rule #21)
    const int swzChunk = ((lane & 7) ^ ((lane >> 3) & 7)) * 8;
    const unsigned short* aSrc = xb + (size_t)t * kB * kD +
        (size_t)(rt * 128 + wid * 16 + (lane >> 3)) * kD + swzChunk;
    const int slot = (wid < 4) ? wid : (4 + t * 4 + (wid - 4));
    const unsigned short* bSrc = Wt + (size_t)slot * kDE * kD +
        (size_t)(n0 + (lane >> 3)) * kD + swzChunk;

    // fragment read offsets
    const int rAbase = (wr * 64 + (lane & 15)) * 64;
    const int bOff   = (wc * 16 + (lane & 15)) * 64;
    const int lx     = lane & 7;
    const int kg     = lane >> 4;

    f32x4 acc[8][4];
#pragma unroll
    for (int e = 0; e < 8; e++)
#pragma unroll
        for (int m = 0; m < 4; m++) acc[e][m] = (f32x4){0.f, 0.f, 0.f, 0.f};

    bf16x8 af[4];
    bf16x8 bfr[4];

#define STAGE_A(buf, ktn)                                                      \
    _Pragma("unroll")                                                          \
    for (int i = 0; i < 2; i++)                                                \
        async16(&As[buf][wid * 1024 + i * 512], aSrc + (ktn) * 64 + i * 8 * kD);

#define STAGE_B(buf, ktn, j0, jn)                                              \
    _Pragma("unroll")                                                          \
    for (int j = (j0); j < (j0) + (jn); j++)                                   \
        async16(&Bs[buf][wid * 4096 + j * 512], bSrc + (ktn) * 64 + j * 8 * kD);

#define READ_A(buf, ks)                                                        \
    _Pragma("unroll")                                                          \
    for (int m = 0; m < 4; m++)                                                \
        af[m] = *(const bf16x8*)&As[buf][rAbase + m * 1024 +                   \
                                         ((((ks) * 4 + kg) ^ lx) << 3)];

#define READ_B(buf, ks, e0)                                                    \
    _Pragma("unroll")                                                          \
    for (int i = 0; i < 4; i++)                                                \
        bfr[i] = *(const bf16x8*)&Bs[buf][((e0) + i) * 4096 + bOff +           \
                                          ((((ks) * 4 + kg) ^ lx) << 3)];

#define MFMA_CLUSTER(e0)                                                       \
    asm volatile("s_waitcnt lgkmcnt(0)" ::: "memory");                         \
    __builtin_amdgcn_sched_barrier(0);                                         \
    __builtin_amdgcn_s_setprio(1);                                             \
    _Pragma("unroll")                                                          \
    for (int i = 0; i < 4; i++)                                                \
        _Pragma("unroll")                                                      \
        for (int m = 0; m < 4; m++)                                            \
            acc[(e0) + i][m] = __builtin_amdgcn_mfma_f32_16x16x32_bf16(        \
                af[m], bfr[i], acc[(e0) + i][m], 0, 0, 0);                     \
    __builtin_amdgcn_s_setprio(0);

#define STEP(cur, nxt, ktn)                                                    \
    {                                                                          \
        /* ph0: A-stage, tile-cur landed, experts 0-3 ks0 */                   \
        STAGE_A(nxt, ktn);                                                     \
        asm volatile("s_waitcnt vmcnt(2)" ::: "memory");                       \
        __builtin_amdgcn_s_barrier();                                          \
        __builtin_amdgcn_sched_barrier(0);                                     \
        READ_A(cur, 0);                                                        \
        READ_B(cur, 0, 0);                                                     \
        MFMA_CLUSTER(0);                                                       \
        /* ph1: experts 4-7 ks0 */                                             \
        READ_B(cur, 0, 4);                                                     \
        STAGE_B(nxt, ktn, 0, 3);                                               \
        __builtin_amdgcn_s_barrier();                                          \
        MFMA_CLUSTER(4);                                                       \
        /* ph2: experts 0-3 ks1 */                                             \
        READ_A(cur, 1);                                                        \
        READ_B(cur, 1, 0);                                                     \
        STAGE_B(nxt, ktn, 3, 3);                                               \
        __builtin_amdgcn_s_barrier();                                          \
        MFMA_CLUSTER(0);                                                       \
        /* ph3: experts 4-7 ks1 */                                             \
        READ_B(cur, 1, 4);                                                     \
        STAGE_B(nxt, ktn, 6, 2);                                               \
        __builtin_amdgcn_s_barrier();                                          \
        MFMA_CLUSTER(4);                                                       \
        /* trailing: all reads of buf cur done -> cur stageable next step */   \
        __builtin_amdgcn_s_barrier();                                          \
        __builtin_amdgcn_sched_barrier(0);                                     \
    }

    // prologue: tile 0 into buf 0
    STAGE_A(0, 0);
    STAGE_B(0, 0, 0, 8);

    for (int kt2 = 0; kt2 < 8; ++kt2) {
        const int ka = kt2 * 2 + 1;          // next-tile index for even step
        const int kb = (kt2 * 2 + 2) & 15;   // next-tile index for odd step
        STEP(0, 1, ka)
        STEP(1, 0, kb)
    }
    asm volatile("s_waitcnt vmcnt(0)" ::: "memory");

#undef STAGE_A
#undef STAGE_B
#undef READ_A
#undef READ_B
#undef MFMA_CLUSTER
#undef STEP

    // ---- epilogue: out = sum_e g_e * relu(acc[e] + b_e) ----
    const int col = n0 + wc * 16 + (lane & 15);
    float bv[8];
#pragma unroll
    for (int e = 0; e < 8; e++) bv[e] = bc[(t * 8 + e) * kDE + col];

#pragma unroll
    for (int m = 0; m < 4; m++) {
        const int r0 = rt * 128 + wr * 64 + m * 16 + kg * 4;
        f32x4 oq = (f32x4){0.f, 0.f, 0.f, 0.f};
#pragma unroll
        for (int q = 0; q < 4; q++) {
            const float* gp = g + ((size_t)t * kB + r0 + q) * 8;
            const float4 ga = *(const float4*)gp;
            const float4 gb = *(const float4*)(gp + 4);
            const float gv[8] = {ga.x, ga.y, ga.z, ga.w, gb.x, gb.y, gb.z, gb.w};
            float s = 0.f;
#pragma unroll
            for (int e = 0; e < 8; e++)
                s += gv[e] * fmaxf(acc[e][m][q] + bv[e], 0.f);
            oq[q] = s;
        }
#pragma unroll
        for (int q = 0; q < 4; q++)
            out[((size_t)(r0 + q) * 2 + t) * kDE + col] = oq[q];
    }
}

extern "C" void kernel_launch(void* const* d_in, const int* in_sizes, int n_in,
                              void* d_out, int out_size, void* d_ws, size_t ws_size,
                              hipStream_t stream) {
    const float* x0  = (const float*)d_in[0];
    const float* x1  = (const float*)d_in[1];
    const float* Wsh = (const float*)d_in[2];
    const float* bsh = (const float*)d_in[3];
    const float* Wsp = (const float*)d_in[4];
    const float* bsp = (const float*)d_in[5];
    const float* Wg  = (const float*)d_in[6];
    const float* bg  = (const float*)d_in[7];
    float* out = (float*)d_out;

    // ws layout (bytes): xb 67108864 | Wt 12582912 | g 1048576 | bc 32768
    char* ws = (char*)d_ws;
    unsigned short* xb = (unsigned short*)ws;
    unsigned short* Wt = (unsigned short*)(ws + 67108864);
    float* g  = (float*)(ws + 67108864 + 12582912);
    float* bc = (float*)(ws + 67108864 + 12582912 + 1048576);

    prep_w<<<dim3(32, 16, 12), dim3(32, 8), 0, stream>>>(Wsh, Wsp, Wt);
    prep_b<<<dim3(32), dim3(256), 0, stream>>>(bsh, bsp, bc);
    conv_gate<<<dim3(8192), dim3(256), 0, stream>>>(x0, x1, Wg, bg, xb, g);
    moe_gemm<<<dim3(2048), dim3(512), 0, stream>>>(xb, Wt, g, bc, out);
}